// Round 14
// baseline (123.781 us; speedup 1.0000x reference)
//
#include <hip/hip_runtime.h>
#include <hip/hip_bf16.h>
#include <cstdint>

#define TOK 1024      // B*L
#define LSEQ 512
#define DMODEL 1024
#define DPROJ 6464
#define DPROJP 6528   // padded to 51*128
#define DSSM 2048
#define NHEADS 32
#define HEADDIM 64
#define DSTATE 128
#define NCH 8
#define CL 64

typedef __attribute__((ext_vector_type(4))) float f32x4;
typedef _Float16 f16;
typedef __attribute__((ext_vector_type(8))) _Float16 f16x8;
typedef __attribute__((ext_vector_type(4))) _Float16 f16x4;
typedef __attribute__((ext_vector_type(8))) ushort u16x8;

__device__ __forceinline__ float silu_f(float x){
  return x*__builtin_amdgcn_rcpf(1.f+__expf(-x));
}

__device__ __forceinline__ void gload16(const void* g, void* l){
  __builtin_amdgcn_global_load_lds(
      (const __attribute__((address_space(1))) unsigned int*)g,
      (__attribute__((address_space(3))) unsigned int*)l, 16, 0, 0);
}

// ------------- fused prep: W_in^T->f16, W_out^T->f16, u->f16 -------------
__global__ __launch_bounds__(256) void prep_kernel(
    const float* __restrict__ W_in, const float* __restrict__ W_out,
    const float* __restrict__ u,
    f16* __restrict__ WT, f16* __restrict__ WoT, f16* __restrict__ uhf)
{
  int b = blockIdx.x;
  if (b < 6528 + 2048){
    __shared__ float tile[32][33];
    const float* W; f16* T; int K, N, bx, by;
    if (b < 6528){ W = W_in;  T = WT;  K = DMODEL; N = DPROJ;  bx = b % 204;      by = b / 204; }
    else         { int ib = b - 6528; W = W_out; T = WoT; K = DSSM; N = DMODEL; bx = ib & 31; by = ib >> 5; }
    int tx = threadIdx.x & 31, ty = threadIdx.x >> 5;
    int n = bx*32 + tx;
    #pragma unroll
    for (int i=0;i<4;i++){
      int k = by*32 + ty + i*8;
      tile[ty+i*8][tx] = (n < N) ? W[(size_t)k*N + n] : 0.f;
    }
    __syncthreads();
    #pragma unroll
    for (int i=0;i<4;i++){
      int nn = bx*32 + ty + i*8;
      int kk = by*32 + tx;
      T[(size_t)nn*K + kk] = (f16)tile[tx][ty+i*8];
    }
  } else {
    int i = (b - 8576)*256 + threadIdx.x;
    f32x4 v = ((const f32x4*)u)[i];
    f16x4 h;
    #pragma unroll
    for (int j=0;j<4;j++) h[j] = (f16)v[j];
    *(f16x4*)&uhf[(size_t)i*4] = h;
  }
}

// ------------- GEMM f16: 128x128 tile, 512 threads, BK=64, dbuf+counted vmcnt -------------
// MODE 0: in-proj fused epilogue -> zxh f16 (full), dtb f32 (cols 4352..4383), thT f16 (cols 4416..6463, transposed)
// MODE 1: out-proj split-K, f16 partials
template<int MODE>
__global__ __launch_bounds__(512) void gemmh_kernel(
    const f16* __restrict__ A, const f16* __restrict__ B,
    f16* __restrict__ C, float* __restrict__ dtb, f16* __restrict__ thT,
    int K, int kLen, int ldc, int nbn, int chunk)
{
  __shared__ ushort sA[2][8192], sB[2][8192];
  int bid = blockIdx.x;
  int newL = (bid & 7)*chunk + (bid >> 3);   // XCD-chunked swizzle (grid = 8*chunk)
  int bm = newL & 7;
  int pan = newL >> 3;
  int bn = pan % nbn;
  int z  = pan / nbn;
  int k0 = z * kLen;
  size_t zoff = (size_t)z * 1024 * ldc;

  int tid = threadIdx.x;
  int wid = tid >> 6, lane = tid & 63;
  int wr = wid >> 2, wc = wid & 3;           // 2x4 wave grid -> 64x32 per wave
  int fr = lane & 15, kq = lane >> 4;
  f32x4 acc[4][2] = {};

  int srow = tid & 127;
  int skg  = (tid >> 7) & 3;                 // 0..3
  const f16* gA = A + (size_t)(bm*128+srow)*K + k0 + skg*8;
  const f16* gB = B + (size_t)(bn*128+srow)*K + k0 + skg*8;

  int rA = kq*1024 + (wr*64 + fr)*8;
  int rB = kq*1024 + (wc*32 + fr)*8;
  int NK = kLen >> 6;

#define STAGE(buf, kk) { \
    const f16* pa = gA + (kk)*64; \
    const f16* pb = gB + (kk)*64; \
    gload16(pa,      &sA[buf][tid*8]); \
    gload16(pa + 32, &sA[buf][tid*8 + 4096]); \
    gload16(pb,      &sB[buf][tid*8]); \
    gload16(pb + 32, &sB[buf][tid*8 + 4096]); \
  }

  STAGE(0, 0)
  STAGE(1, 1)

  for (int ks=0; ks<NK; ks++){
    int cur = ks & 1;
    if (ks == NK-1) asm volatile("s_waitcnt vmcnt(0)" ::: "memory");
    else            asm volatile("s_waitcnt vmcnt(4)" ::: "memory");
    __builtin_amdgcn_s_barrier();
    f16x8 af0[4], af1[4], bf0[2], bf1[2];
    #pragma unroll
    for (int i=0;i<4;i++){
      af0[i] = *(const f16x8*)&sA[cur][rA + i*128];
      af1[i] = *(const f16x8*)&sA[cur][rA + 4096 + i*128];
    }
    #pragma unroll
    for (int j=0;j<2;j++){
      bf0[j] = *(const f16x8*)&sB[cur][rB + j*128];
      bf1[j] = *(const f16x8*)&sB[cur][rB + 4096 + j*128];
    }
    asm volatile("s_waitcnt lgkmcnt(0)" ::: "memory");
    __builtin_amdgcn_sched_barrier(0);
    __builtin_amdgcn_s_barrier();
    if (ks+2 < NK) STAGE(cur, ks+2)
    #pragma unroll
    for (int i=0;i<4;i++)
      #pragma unroll
      for (int j=0;j<2;j++)
        acc[i][j] = __builtin_amdgcn_mfma_f32_16x16x32_f16(af0[i], bf0[j], acc[i][j], 0,0,0);
    #pragma unroll
    for (int i=0;i<4;i++)
      #pragma unroll
      for (int j=0;j<2;j++)
        acc[i][j] = __builtin_amdgcn_mfma_f32_16x16x32_f16(af1[i], bf1[j], acc[i][j], 0,0,0);
  }
#undef STAGE
  int rq = kq * 4;
  #pragma unroll
  for (int i=0;i<4;i++){
    #pragma unroll
    for (int j=0;j<2;j++){
      int row = bm*128 + wr*64 + i*16 + rq;
      int col = bn*128 + wc*32 + j*16 + fr;
      #pragma unroll
      for (int q=0;q<4;q++){
        float av = acc[i][j][q];
        f16 hv = (f16)av;
        if constexpr (MODE == 0){
          int r = row + q;
          C[(size_t)r*ldc + col] = hv;
          if (col >= 4352 && col < 4384)
            dtb[r*32 + (col - 4352)] = av;
          if (col >= 4416 && col < 4416 + 2048){   // theta only; EXCLUDE pad cols >= 6464
            int bb = r >> 9, l = r & 511;
            thT[((size_t)(bb*2048 + (col - 4416)))*512 + l] = hv;
          }
        } else {
          C[zoff + (size_t)(row+q)*ldc + col] = hv;
        }
      }
    }
  }
}

// ------------- reduce 4 split-K f16 partials -> f32 out -------------
__global__ __launch_bounds__(256) void red4_kernel(const f16* __restrict__ P, float* __restrict__ O){
  int i = blockIdx.x*256 + threadIdx.x;
  f16x4 a = ((const f16x4*)P)[i];
  f16x4 b = ((const f16x4*)P)[i + 262144];
  f16x4 c = ((const f16x4*)P)[i + 2*262144];
  f16x4 d = ((const f16x4*)P)[i + 3*262144];
  f32x4 v;
  #pragma unroll
  for (int j=0;j<4;j++) v[j] = (float)a[j] + (float)b[j] + (float)c[j] + (float)d[j];
  ((f32x4*)O)[i] = v;
}

// ------------- cumsum(theta f16) + cos/sin partial means (8 heads per block, 4 partials) -------------
__global__ __launch_bounds__(512) void cum2_kernel(const f16* __restrict__ thT,
    float* __restrict__ cosm, float* __restrict__ sinm)
{
  __shared__ float wsum[8];
  int blk = blockIdx.x;            // 512 = b(2) x hd(64) x q(4)
  int q = blk & 3, hd = (blk >> 2) & 63, b = blk >> 8;
  int l = threadIdx.x, lane = l & 63, w = l >> 6;
  float accc = 0.f, accs = 0.f;
  const f16* base = thT + (size_t)b*2048*512 + (size_t)(q*8)*64*512 + (size_t)hd*512;
  for (int h = 0; h < 8; h++){
    float x = (float)base[(size_t)h*64*512 + l];
    #pragma unroll
    for (int m=1; m<64; m<<=1){
      float v = __shfl_up(x, m, 64);
      if (lane >= m) x += v;
    }
    if (lane == 63) wsum[w] = x;
    __syncthreads();
    float pre = 0.f;
    for (int i=0;i<w;i++) pre += wsum[i];
    x += pre;
    float s, c;
    __sincosf(x, &s, &c);
    accc += c; accs += s;
    __syncthreads();
  }
  int t = b*LSEQ + l;
  cosm[q*TOK*64 + t*64+hd] = accc*(1.f/32.f);
  sinm[q*TOK*64 + t*64+hd] = accs*(1.f/32.f);
}

// ------------- per-token: B/C rms+rope (f16 in/out), dt(f32)/dA/lam/lamg pack -------------
__global__ __launch_bounds__(256) void ew_kernel(const f16* __restrict__ zxh,
    const float* __restrict__ dtb,
    const float* __restrict__ cosm, const float* __restrict__ sinm,
    const float* __restrict__ dt_bias, const float* __restrict__ A_log,
    const float* __restrict__ B_bias, const float* __restrict__ C_bias,
    const float* __restrict__ Bnw, const float* __restrict__ Cnw,
    f16* __restrict__ Bg, f16* __restrict__ Cg, float4* __restrict__ scal)
{
  int t = blockIdx.x; int tid = threadIdx.x;
  __shared__ float red[256];
  __shared__ float nb[128], nc[128];
  const f16* row = zxh + (size_t)t*DPROJP;
  float v;
  if (tid < 128) v = (float)row[4096 + tid] + B_bias[tid];
  else           v = (float)row[4224 + (tid-128)] + C_bias[tid-128];
  red[tid] = v*v;
  __syncthreads();
  #pragma unroll
  for (int s=64; s>0; s>>=1){
    if ((tid & 127) < s) red[tid] += red[tid + s];
    __syncthreads();
  }
  float ms = red[(tid < 128) ? 0 : 128] * (1.f/128.f);
  float rs = rsqrtf(ms + 1e-5f);
  float w  = (tid < 128) ? Bnw[tid] : Cnw[tid-128];
  float nv = v * rs * w;
  if (tid < 128) nb[tid] = nv; else nc[tid-128] = nv;
  __syncthreads();
  if (tid < 64){
    float c = cosm[t*64+tid] + cosm[TOK*64 + t*64+tid] + cosm[2*TOK*64 + t*64+tid] + cosm[3*TOK*64 + t*64+tid];
    float s = sinm[t*64+tid] + sinm[TOK*64 + t*64+tid] + sinm[2*TOK*64 + t*64+tid] + sinm[3*TOK*64 + t*64+tid];
    float a = nb[tid], bq = nb[tid+64];
    Bg[(size_t)t*128 + tid]      = (f16)(a*c - bq*s);
    Bg[(size_t)t*128 + 64 + tid] = (f16)(bq*c + a*s);
  } else if (tid < 128){
    int i = tid - 64;
    float c = cosm[t*64+i] + cosm[TOK*64 + t*64+i] + cosm[2*TOK*64 + t*64+i] + cosm[3*TOK*64 + t*64+i];
    float s = sinm[t*64+i] + sinm[TOK*64 + t*64+i] + sinm[2*TOK*64 + t*64+i] + sinm[3*TOK*64 + t*64+i];
    float a = nc[i], bq = nc[i+64];
    Cg[(size_t)t*128 + i]      = (f16)(a*c - bq*s);
    Cg[(size_t)t*128 + 64 + i] = (f16)(bq*c + a*s);
  } else if (tid < 160){
    int hh = tid - 128;
    float dtr = dtb[t*32 + hh] + dt_bias[hh];
    float dtv = (dtr > 20.f) ? dtr : log1pf(expf(dtr));
    float dA  = expf(-dtv * expf(A_log[hh]));
    float lr  = (float)row[4384 + hh];
    float lam = 1.f/(1.f + expf(-lr));
    float lg = lam;
    #pragma unroll
    for (int m=1;m<32;m<<=1) lg += __shfl_xor(lg, m, 64);
    lg *= (1.f/32.f);
    scal[(size_t)t*32 + hh] = make_float4(dtv, dA, lam, lg);
  }
}

// ------------- pass 1: per-(b,h,chunk) attention-form local scan, all-f16 LDS -------------
#define CST 136   // f16 row stride for [64][128] tiles
#define SST 72    // f16 row stride for [*][64] tiles
__global__ __launch_bounds__(256, 2) void scanA_kernel(
    const f16* __restrict__ zxh, const f16* __restrict__ Bg,
    const f16* __restrict__ Cg, const float4* __restrict__ scal,
    const float* __restrict__ A_log, const float* __restrict__ Dp,
    f16* __restrict__ ypart, f16* __restrict__ hcarry,
    float* __restrict__ clog, float* __restrict__ AtotB)
{
  __shared__ __align__(16) f16 smC[64*CST];   // C chunk [t][d]; later aliased by S' [t][s]
  __shared__ __align__(16) f16 smB[64*CST];   // B_eff [s][d]
  __shared__ __align__(16) f16 smBT[128*SST]; // B_eff^T * w[s]  [d][s]
  __shared__ __align__(16) f16 smX[64*SST];   // xe^T [p][s]
  __shared__ __align__(16) float sDt[64], sLam[64], sLg[64], sCl[64], sW[64];
  f16* sSp = smC;

  int blk = blockIdx.x;            // (b*32+h)*8 + c
  int c = blk & 7, h = (blk>>3)&31, b = blk>>8;
  int idx = blk;
  int t0 = b*LSEQ + c*CL;
  int tid = threadIdx.x;
  int w = tid >> 6, lane = tid & 63;
  int fr = lane & 15, kq = lane >> 4;

  // ---- phase 0: stage C (f16 direct copy) + wave0 scalar prep ----
  {
    int s = tid >> 2, dq4 = (tid & 3) * 32;
    const ushort* src = (const ushort*)(Cg + (size_t)(t0+s)*128 + dq4);
    ushort* dst = (ushort*)(smC + s*CST + dq4);
    #pragma unroll
    for (int i=0;i<4;i++) *(u16x8*)(dst + i*8) = *(const u16x8*)(src + i*8);
  }
  if (tid < 64){
    float4 sc = scal[(size_t)(t0+tid)*32 + h];
    float a  = __expf(A_log[h]);
    float cl = -sc.x * a * 1.44269504088896f;   // log2(dA)
    #pragma unroll
    for (int m=1; m<64; m<<=1){
      float v = __shfl_up(cl, m, 64);
      if (lane >= m) cl += v;
    }
    float cl63 = __shfl(cl, 63, 64);
    sDt[tid] = sc.x; sLam[tid] = sc.z; sLg[tid] = sc.w;
    sCl[tid] = cl;
    sW[tid]  = exp2f(cl63 - cl) * sc.x;
    clog[(size_t)idx*64 + tid] = cl;
    if (tid == 63) AtotB[idx] = exp2f(cl63);
  }
  __syncthreads();

  // ---- phase 1: stage B_eff (+transposed*w) and xe, f16 ----
  {
    int s = tid >> 2, dq4 = (tid & 3) * 32;
    float lg = sLg[s], wgt = sW[s];
    bool zp = (s == 0 && c == 0);
    const f16* bc_p = Bg + (size_t)(t0+s)*128 + dq4;
    const f16* bp_p = Bg + (size_t)(t0+s-1)*128 + dq4;
    #pragma unroll
    for (int i=0;i<32;i+=4){
      f16x4 bc4 = *(const f16x4*)(bc_p + i);
      f16x4 bp4 = {0,0,0,0};
      if (!zp) bp4 = *(const f16x4*)(bp_p + i);
      f16x4 be4;
      #pragma unroll
      for (int e=0;e<4;e++){
        float bc = (float)bc4[e], bp = (float)bp4[e];
        float be = bp + lg*(bc - bp);
        be4[e] = (f16)be;
        smBT[(dq4+i+e)*SST + s] = (f16)(be * wgt);
      }
      *(f16x4*)(smB + s*CST + dq4 + i) = be4;
    }
  }
  {
    int p = tid & 63, sg = tid >> 6;
    int s0 = sg*16;
    const f16* xbase = zxh + 2048 + h*64 + p;
    float xp_ = 0.f;
    if (!(s0 == 0 && c == 0))
      xp_ = silu_f((float)xbase[(size_t)(t0+s0-1)*DPROJP]);
    #pragma unroll
    for (int i=0;i<16;i++){
      int s = s0 + i;
      float xs = silu_f((float)xbase[(size_t)(t0+s)*DPROJP]);
      smX[p*SST + s] = (f16)(xp_ + sLam[s]*(xs - xp_));
      xp_ = xs;
    }
  }
  __syncthreads();

  // ---- phase 2: GEMM1  S = C @ Beff^T (K=128) ----
  int tq = w >> 1, sq = w & 1;
  f32x4 acc1[2][2] = {};
  #pragma unroll
  for (int kt=0; kt<4; kt++){
    f16x8 ah[2], bh[2];
    #pragma unroll
    for (int i=0;i<2;i++)
      ah[i] = *(const f16x8*)&smC[(tq*32 + i*16 + fr)*CST + kt*32 + kq*8];
    #pragma unroll
    for (int j=0;j<2;j++)
      bh[j] = *(const f16x8*)&smB[(sq*32 + j*16 + fr)*CST + kt*32 + kq*8];
    #pragma unroll
    for (int i=0;i<2;i++)
      #pragma unroll
      for (int j=0;j<2;j++)
        acc1[i][j] = __builtin_amdgcn_mfma_f32_16x16x32_f16(ah[i], bh[j], acc1[i][j], 0,0,0);
  }
  // mask: S'[t,s] = S * exp2(cl_t - cl_s) * dt_s for s<=t else 0
  #pragma unroll
  for (int i=0;i<2;i++){
    int tb = tq*32 + i*16 + kq*4;
    f32x4 clt = *(const f32x4*)&sCl[tb];
    #pragma unroll
    for (int j=0;j<2;j++){
      int scol = sq*32 + j*16 + fr;
      float cls = sCl[scol], dts = sDt[scol];
      #pragma unroll
      for (int q=0;q<4;q++){
        float m = (tb+q >= scol) ? exp2f(clt[q]-cls)*dts : 0.f;
        acc1[i][j][q] *= m;
      }
    }
  }
  __syncthreads();
  #pragma unroll
  for (int i=0;i<2;i++){
    int tb = tq*32 + i*16 + kq*4;
    #pragma unroll
    for (int j=0;j<2;j++){
      int scol = sq*32 + j*16 + fr;
      #pragma unroll
      for (int q=0;q<4;q++)
        sSp[(tb+q)*SST + scol] = (f16)acc1[i][j][q];
    }
  }
  __syncthreads();

  float Dh = Dp[h];
  // ---- phase 3: GEMM2  Y = S' @ Xe  (K=64) + D*xe, write slice0 (f16) ----
  {
    f32x4 acc2[2][2] = {};
    #pragma unroll
    for (int kt=0; kt<2; kt++){
      f16x8 ah[2], bh[2];
      #pragma unroll
      for (int i=0;i<2;i++)
        ah[i] = *(const f16x8*)&sSp[(tq*32 + i*16 + fr)*SST + kt*32 + kq*8];
      #pragma unroll
      for (int j=0;j<2;j++)
        bh[j] = *(const f16x8*)&smX[(sq*32 + j*16 + fr)*SST + kt*32 + kq*8];
      #pragma unroll
      for (int i=0;i<2;i++)
        #pragma unroll
        for (int j=0;j<2;j++)
          acc2[i][j] = __builtin_amdgcn_mfma_f32_16x16x32_f16(ah[i], bh[j], acc2[i][j], 0,0,0);
    }
    #pragma unroll
    for (int i=0;i<2;i++){
      int tb = tq*32 + i*16 + kq*4;
      #pragma unroll
      for (int j=0;j<2;j++){
        int pc = sq*32 + j*16 + fr;
        #pragma unroll
        for (int q=0;q<4;q++){
          float y = acc2[i][j][q] + Dh * (float)smX[pc*SST + tb + q];
          ypart[(size_t)(t0+tb+q)*DSSM + h*64 + pc] = (f16)y;
        }
      }
    }
  }

  // ---- phase 4: GEMM4  H_local = Xe @ (w-scaled B)^T  (K=64), f16 out ----
  {
    f32x4 acc4[2][4] = {};
    int ph = w >> 1, dh = w & 1;
    #pragma unroll
    for (int kt=0; kt<2; kt++){
      f16x8 ah[2], bh[4];
      #pragma unroll
      for (int i=0;i<2;i++)
        ah[i] = *(const f16x8*)&smX[(ph*32 + i*16 + fr)*SST + kt*32 + kq*8];
      #pragma unroll
      for (int j=0;j<4;j++)
        bh[j] = *(const f16x8*)&smBT[(dh*64 + j*16 + fr)*SST + kt*32 + kq*8];
      #pragma unroll
      for (int i=0;i<2;i++)
        #pragma unroll
        for (int j=0;j<4;j++)
          acc4[i][j] = __builtin_amdgcn_mfma_f32_16x16x32_f16(ah[i], bh[j], acc4[i][j], 0,0,0);
    }
    size_t hb = (size_t)idx * 64 * 128;
    #pragma unroll
    for (int i=0;i<2;i++){
      int pb = ph*32 + i*16 + kq*4;
      #pragma unroll
      for (int j=0;j<4;j++){
        int dc = dh*64 + j*16 + fr;
        #pragma unroll
        for (int q=0;q<4;q++)
          hcarry[hb + (size_t)(pb+q)*128 + dc] = (f16)acc4[i][j][q];
      }
    }
  }
}

// ------------- pass 2: propagate carries across chunks (f16 storage, f32 math) -------------
__global__ __launch_bounds__(256) void scan2_kernel(f16* __restrict__ hcarry,
    const float* __restrict__ AtotB)
{
  int idx = blockIdx.x*256 + threadIdx.x;
  int d = idx & 127, pp = (idx >> 7) & 63, h = (idx >> 13) & 31, b = idx >> 18;
  size_t base = ((size_t)(b*32+h)*512 + pp)*128 + d;
  float Hin = 0.f;
  #pragma unroll
  for (int c=0; c<NCH; c++){
    float Atot = AtotB[(b*32+h)*8 + c];
    float S = (float)hcarry[base + (size_t)c*8192];
    hcarry[base + (size_t)c*8192] = (f16)Hin;
    Hin = Atot*Hin + S;
  }
}

// ------------- pass 3: Y2 = exp2(cl_t) * C @ Hin^T  (K=128), f16 LDS, write slice1 f16 -------------
__global__ __launch_bounds__(256) void scanB_kernel(
    const f16* __restrict__ Cg, const f16* __restrict__ hcarry,
    const float* __restrict__ clog, f16* __restrict__ ypart)
{
  __shared__ __align__(16) f16 smC[64*CST];
  __shared__ __align__(16) f16 smH[64*CST];   // Hin [p][d]
  __shared__ __align__(16) float sK[64];
  int blk = blockIdx.x;
  int c = blk & 7, h = (blk>>3)&31, b = blk>>8;
  int idx = blk;
  int t0 = b*LSEQ + c*CL;
  int tid = threadIdx.x;
  int w = tid >> 6, lane = tid & 63;
  int fr = lane & 15, kq = lane >> 4;
  {
    int s = tid >> 2, dq4 = (tid & 3) * 32;
    const ushort* src = (const ushort*)(Cg + (size_t)(t0+s)*128 + dq4);
    ushort* dst = (ushort*)(smC + s*CST + dq4);
    #pragma unroll
    for (int i=0;i<4;i++) *(u16x8*)(dst + i*8) = *(const u16x8*)(src + i*8);
    const ushort* hs = (const ushort*)(hcarry + (size_t)idx*8192 + (size_t)s*128 + dq4);
    ushort* hd = (ushort*)(smH + s*CST + dq4);
    #pragma unroll
    for (int i=0;i<4;i++) *(u16x8*)(hd + i*8) = *(const u16x8*)(hs + i*8);
  }
  if (tid < 64) sK[tid] = exp2f(clog[(size_t)idx*64 + tid]);
  __syncthreads();

  int tq = w >> 1, pq = w & 1;
  f32x4 acc[2][2] = {};
  #pragma unroll
  for (int kt=0; kt<4; kt++){
    f16x8 ah[2], bh[2];
    #pragma unroll
    for (int i=0;i<2;i++)
      ah[i] = *(const f16x8*)&smC[(tq*32 + i*16 + fr)*CST + kt*32 + kq*8];
    #pragma unroll
    for (int j=0;j<2;j++)
      bh[j] = *(const f16x8*)&smH[(pq*32 + j*16 + fr)*CST + kt*32 + kq*8];
    #pragma unroll
    for (int i=0;i<2;i++)
      #pragma unroll
      for (int j=0;j<2;j++)
        acc[i][j] = __builtin_amdgcn_mfma_f32_16x16x32_f16(ah[i], bh[j], acc[i][j], 0,0,0);
  }
  #pragma unroll
  for (int i=0;i<2;i++){
    int tb = tq*32 + i*16 + kq*4;
    f32x4 kv = *(const f32x4*)&sK[tb];
    #pragma unroll
    for (int j=0;j<2;j++){
      int pc = pq*32 + j*16 + fr;
      #pragma unroll
      for (int q=0;q<4;q++)
        ypart[(size_t)TOK*DSSM + (size_t)(t0+tb+q)*DSSM + h*64 + pc] = (f16)(acc[i][j][q]*kv[q]);
    }
  }
}

// ------------- final: sum 2 f16 partials, *silu(z f16), rms*norm_w -> f16 -------------
__global__ __launch_bounds__(256) void fin_kernel(const f16* __restrict__ zxh,
    const f16* __restrict__ ypart, const float* __restrict__ normw,
    f16* __restrict__ yf)
{
  int t = blockIdx.x; int tid = threadIdx.x;
  __shared__ float red[256];
  float vloc[8];
  float ss = 0.f;
  #pragma unroll
  for (int i=0;i<8;i++){
    int cc = tid + i*256;
    float y = (float)ypart[(size_t)t*DSSM + cc]
            + (float)ypart[(size_t)(TOK + t)*DSSM + cc];
    float z = (float)zxh[(size_t)t*DPROJP + cc];
    float v = y * (z / (1.f + expf(-z)));
    vloc[i] = v; ss += v*v;
  }
  red[tid] = ss; __syncthreads();
  #pragma unroll
  for (int s=128; s>0; s>>=1){ if (tid < s) red[tid] += red[tid+s]; __syncthreads(); }
  float rs = rsqrtf(red[0]*(1.f/2048.f) + 1e-5f);
  #pragma unroll
  for (int i=0;i<8;i++){
    int cc = tid + i*256;
    yf[(size_t)t*DSSM + cc] = (f16)(vloc[i]*rs*normw[cc]);
  }
}

extern "C" void kernel_launch(void* const* d_in, const int* in_sizes, int n_in,
                              void* d_out, int out_size, void* d_ws, size_t ws_size,
                              hipStream_t stream)
{
  const float* u      = (const float*)d_in[0];
  const float* W_in   = (const float*)d_in[1];
  const float* W_out  = (const float*)d_in[2];
  const float* dt_bias= (const float*)d_in[3];
  const float* A_log  = (const float*)d_in[4];
  const float* Dp     = (const float*)d_in[5];
  const float* B_bias = (const float*)d_in[6];
  const float* C_bias = (const float*)d_in[7];
  const float* Bnw    = (const float*)d_in[8];
  const float* Cnw    = (const float*)d_in[9];
  const float* normw  = (const float*)d_in[10];
  float* out = (float*)d_out;

  char* ws = (char*)d_ws;
  size_t o = 0;
  auto alloc = [&](size_t bytes)->char*{
    char* r = ws + o; o = (o + bytes + 255) & ~(size_t)255; return r;
  };
  f16*  WT   = (f16*)alloc((size_t)DPROJP*DMODEL*2);
  f16*  WoT  = (f16*)alloc((size_t)DMODEL*DSSM*2);
  f16*  uhf  = (f16*)alloc((size_t)TOK*DMODEL*2);
  f16*  yf   = (f16*)alloc((size_t)TOK*DSSM*2);
  f16*  zxh  = (f16*)alloc((size_t)TOK*DPROJP*2);
  float* dtb = (float*)alloc((size_t)TOK*32*4);
  f16*   thT  = (f16*)alloc((size_t)2*2048*512*2);
  float*  cosm = (float*)alloc((size_t)4*TOK*64*4);
  float*  sinm = (float*)alloc((size_t)4*TOK*64*4);
  f16*   Bgb  = (f16*)alloc((size_t)TOK*128*2);
  f16*   Cgb  = (f16*)alloc((size_t)TOK*128*2);
  float4* scal = (float4*)alloc((size_t)TOK*32*16);
  f16*   ypart= (f16*)alloc((size_t)2*TOK*DSSM*2);
  f16*   hcarry=(f16*)alloc((size_t)2*32*NCH*64*128*2);
  float*  clog = (float*)alloc((size_t)512*64*4);
  float*  AtotB= (float*)alloc((size_t)512*4);
  f16*   Cpart =(f16*)alloc((size_t)4*TOK*DMODEL*2);

  // fused prep: W_in^T, W_out^T, u -> f16
  prep_kernel<<<dim3(9600), dim3(256), 0, stream>>>(W_in, W_out, u, WT, WoT, uhf);

  // in-proj with fused epilogue: zxh f16 + dtb f32 + thT f16 (transposed theta, guarded)
  gemmh_kernel<0><<<dim3(408), dim3(512), 0, stream>>>(uhf, WT, zxh, dtb, thT, DMODEL, DMODEL, DPROJP, 51, 51);

  // cumsum + cos/sin (512 blocks, 8 heads each)
  cum2_kernel<<<dim3(512), dim3(512), 0, stream>>>(thT, cosm, sinm);

  // per-token elementwise
  ew_kernel<<<dim3(TOK), dim3(256), 0, stream>>>(zxh, dtb, cosm, sinm, dt_bias, A_log,
                                                 B_bias, C_bias, Bnw, Cnw, Bgb, Cgb, scal);

  // attention-form chunked scan (f16 intermediates)
  scanA_kernel<<<dim3(512),  dim3(256), 0, stream>>>(zxh, Bgb, Cgb, scal, A_log, Dp,
                                                     ypart, hcarry, clog, AtotB);
  scan2_kernel<<<dim3(2048), dim3(256), 0, stream>>>(hcarry, AtotB);
  scanB_kernel<<<dim3(512),  dim3(256), 0, stream>>>(Cgb, hcarry, clog, ypart);

  // gate + rms -> f16
  fin_kernel<<<dim3(TOK), dim3(256), 0, stream>>>(zxh, ypart, normw, yf);

  // out-proj: split-K=4, f16 partials
  gemmh_kernel<1><<<dim3(256), dim3(512), 0, stream>>>(yf, WoT, Cpart, nullptr, nullptr, DSSM, 512, DMODEL, 8, 32);
  red4_kernel<<<dim3(TOK*DMODEL/1024), dim3(256), 0, stream>>>(Cpart, out);
}

// Round 15
// 114.720 us; speedup vs baseline: 1.0790x; 1.0790x over previous
//
#include <hip/hip_runtime.h>
#include <hip/hip_bf16.h>
#include <cstdint>

#define TOK 1024      // B*L
#define LSEQ 512
#define DMODEL 1024
#define DPROJ 6464
#define DPROJP 6528   // padded to 51*128
#define DSSM 2048
#define NHEADS 32
#define HEADDIM 64
#define DSTATE 128
#define NCH 8
#define CL 64

typedef __attribute__((ext_vector_type(4))) float f32x4;
typedef _Float16 f16;
typedef __attribute__((ext_vector_type(8))) _Float16 f16x8;
typedef __attribute__((ext_vector_type(4))) _Float16 f16x4;
typedef __attribute__((ext_vector_type(8))) ushort u16x8;

__device__ __forceinline__ float silu_f(float x){
  return x*__builtin_amdgcn_rcpf(1.f+__expf(-x));
}

__device__ __forceinline__ void gload16(const void* g, void* l){
  __builtin_amdgcn_global_load_lds(
      (const __attribute__((address_space(1))) unsigned int*)g,
      (__attribute__((address_space(3))) unsigned int*)l, 16, 0, 0);
}

// ------------- fused prep: W_in^T->f16, W_out^T->f16, u->f16 -------------
__global__ __launch_bounds__(256) void prep_kernel(
    const float* __restrict__ W_in, const float* __restrict__ W_out,
    const float* __restrict__ u,
    f16* __restrict__ WT, f16* __restrict__ WoT, f16* __restrict__ uhf)
{
  int b = blockIdx.x;
  if (b < 6528 + 2048){
    __shared__ float tile[32][33];
    const float* W; f16* T; int K, N, bx, by;
    if (b < 6528){ W = W_in;  T = WT;  K = DMODEL; N = DPROJ;  bx = b % 204;      by = b / 204; }
    else         { int ib = b - 6528; W = W_out; T = WoT; K = DSSM; N = DMODEL; bx = ib & 31; by = ib >> 5; }
    int tx = threadIdx.x & 31, ty = threadIdx.x >> 5;
    int n = bx*32 + tx;
    #pragma unroll
    for (int i=0;i<4;i++){
      int k = by*32 + ty + i*8;
      tile[ty+i*8][tx] = (n < N) ? W[(size_t)k*N + n] : 0.f;
    }
    __syncthreads();
    #pragma unroll
    for (int i=0;i<4;i++){
      int nn = bx*32 + ty + i*8;
      int kk = by*32 + tx;
      T[(size_t)nn*K + kk] = (f16)tile[tx][ty+i*8];
    }
  } else {
    int i = (b - 8576)*256 + threadIdx.x;
    f32x4 v = ((const f32x4*)u)[i];
    f16x4 h;
    #pragma unroll
    for (int j=0;j<4;j++) h[j] = (f16)v[j];
    *(f16x4*)&uhf[(size_t)i*4] = h;
  }
}

// ------------- GEMM f16: 128x128 tile, 512 threads, BK=64, dbuf+counted vmcnt -------------
// MODE 0: in-proj -> zxh f16 + dtb f32 (cols 4352..4383 only)
// MODE 1: out-proj split-K, f16 partials
template<int MODE>
__global__ __launch_bounds__(512) void gemmh_kernel(
    const f16* __restrict__ A, const f16* __restrict__ B,
    f16* __restrict__ C, float* __restrict__ dtb,
    int K, int kLen, int ldc, int nbn, int chunk)
{
  __shared__ ushort sA[2][8192], sB[2][8192];
  int bid = blockIdx.x;
  int newL = (bid & 7)*chunk + (bid >> 3);   // XCD-chunked swizzle (grid = 8*chunk)
  int bm = newL & 7;
  int pan = newL >> 3;
  int bn = pan % nbn;
  int z  = pan / nbn;
  int k0 = z * kLen;
  size_t zoff = (size_t)z * 1024 * ldc;

  int tid = threadIdx.x;
  int wid = tid >> 6, lane = tid & 63;
  int wr = wid >> 2, wc = wid & 3;           // 2x4 wave grid -> 64x32 per wave
  int fr = lane & 15, kq = lane >> 4;
  f32x4 acc[4][2] = {};

  int srow = tid & 127;
  int skg  = (tid >> 7) & 3;                 // 0..3
  const f16* gA = A + (size_t)(bm*128+srow)*K + k0 + skg*8;
  const f16* gB = B + (size_t)(bn*128+srow)*K + k0 + skg*8;

  int rA = kq*1024 + (wr*64 + fr)*8;
  int rB = kq*1024 + (wc*32 + fr)*8;
  int NK = kLen >> 6;

#define STAGE(buf, kk) { \
    const f16* pa = gA + (kk)*64; \
    const f16* pb = gB + (kk)*64; \
    gload16(pa,      &sA[buf][tid*8]); \
    gload16(pa + 32, &sA[buf][tid*8 + 4096]); \
    gload16(pb,      &sB[buf][tid*8]); \
    gload16(pb + 32, &sB[buf][tid*8 + 4096]); \
  }

  STAGE(0, 0)
  STAGE(1, 1)

  for (int ks=0; ks<NK; ks++){
    int cur = ks & 1;
    if (ks == NK-1) asm volatile("s_waitcnt vmcnt(0)" ::: "memory");
    else            asm volatile("s_waitcnt vmcnt(4)" ::: "memory");
    __builtin_amdgcn_s_barrier();
    f16x8 af0[4], af1[4], bf0[2], bf1[2];
    #pragma unroll
    for (int i=0;i<4;i++){
      af0[i] = *(const f16x8*)&sA[cur][rA + i*128];
      af1[i] = *(const f16x8*)&sA[cur][rA + 4096 + i*128];
    }
    #pragma unroll
    for (int j=0;j<2;j++){
      bf0[j] = *(const f16x8*)&sB[cur][rB + j*128];
      bf1[j] = *(const f16x8*)&sB[cur][rB + 4096 + j*128];
    }
    asm volatile("s_waitcnt lgkmcnt(0)" ::: "memory");
    __builtin_amdgcn_sched_barrier(0);
    __builtin_amdgcn_s_barrier();
    if (ks+2 < NK) STAGE(cur, ks+2)
    #pragma unroll
    for (int i=0;i<4;i++)
      #pragma unroll
      for (int j=0;j<2;j++)
        acc[i][j] = __builtin_amdgcn_mfma_f32_16x16x32_f16(af0[i], bf0[j], acc[i][j], 0,0,0);
    #pragma unroll
    for (int i=0;i<4;i++)
      #pragma unroll
      for (int j=0;j<2;j++)
        acc[i][j] = __builtin_amdgcn_mfma_f32_16x16x32_f16(af1[i], bf1[j], acc[i][j], 0,0,0);
  }
#undef STAGE
  int rq = kq * 4;
  #pragma unroll
  for (int i=0;i<4;i++){
    #pragma unroll
    for (int j=0;j<2;j++){
      int row = bm*128 + wr*64 + i*16 + rq;
      int col = bn*128 + wc*32 + j*16 + fr;
      #pragma unroll
      for (int q=0;q<4;q++){
        float av = acc[i][j][q];
        if constexpr (MODE == 0){
          int r = row + q;
          C[(size_t)r*ldc + col] = (f16)av;
          if (col >= 4352 && col < 4384)
            dtb[r*32 + (col - 4352)] = av;
        } else {
          C[zoff + (size_t)(row+q)*ldc + col] = (f16)av;
        }
      }
    }
  }
}

// ------------- reduce 4 split-K f16 partials -> f32 out -------------
__global__ __launch_bounds__(256) void red4_kernel(const f16* __restrict__ P, float* __restrict__ O){
  int i = blockIdx.x*256 + threadIdx.x;
  f16x4 a = ((const f16x4*)P)[i];
  f16x4 b = ((const f16x4*)P)[i + 262144];
  f16x4 c = ((const f16x4*)P)[i + 2*262144];
  f16x4 d = ((const f16x4*)P)[i + 3*262144];
  f32x4 v;
  #pragma unroll
  for (int j=0;j<4;j++) v[j] = (float)a[j] + (float)b[j] + (float)c[j] + (float)d[j];
  ((f32x4*)O)[i] = v;
}

// ------------- transpose theta section: zxh[t][4416+col] (f16) -> thT[b][col][l] (f16) -------------
__global__ __launch_bounds__(256) void thT_kernel(const f16* __restrict__ zxh,
    f16* __restrict__ thT)
{
  __shared__ f16 tile[64][72];
  int ci = blockIdx.x, li = blockIdx.y, bb = blockIdx.z;
  int tx = threadIdx.x & 63, ty = threadIdx.x >> 6;
  const f16* src = zxh + (size_t)(bb*LSEQ + li*64)*DPROJP + 4416 + ci*64;
  #pragma unroll
  for (int i=0;i<16;i++){
    int r = ty + i*4;
    tile[r][tx] = src[(size_t)r*DPROJP + tx];
  }
  __syncthreads();
  f16* dst = thT + ((size_t)bb*2048 + ci*64)*512 + (size_t)li*64;
  #pragma unroll
  for (int i=0;i<16;i++){
    int r = ty + i*4;
    dst[(size_t)r*512 + tx] = tile[tx][r];
  }
}

// ------------- cumsum(theta f16) + cos/sin partial means (8 heads per block, 4 partials) -------------
__global__ __launch_bounds__(512) void cum2_kernel(const f16* __restrict__ thT,
    float* __restrict__ cosm, float* __restrict__ sinm)
{
  __shared__ float wsum[8];
  int blk = blockIdx.x;            // 512 = b(2) x hd(64) x q(4)
  int q = blk & 3, hd = (blk >> 2) & 63, b = blk >> 8;
  int l = threadIdx.x, lane = l & 63, w = l >> 6;
  float accc = 0.f, accs = 0.f;
  const f16* base = thT + (size_t)b*2048*512 + (size_t)(q*8)*64*512 + (size_t)hd*512;
  for (int h = 0; h < 8; h++){
    float x = (float)base[(size_t)h*64*512 + l];
    #pragma unroll
    for (int m=1; m<64; m<<=1){
      float v = __shfl_up(x, m, 64);
      if (lane >= m) x += v;
    }
    if (lane == 63) wsum[w] = x;
    __syncthreads();
    float pre = 0.f;
    for (int i=0;i<w;i++) pre += wsum[i];
    x += pre;
    float s, c;
    __sincosf(x, &s, &c);
    accc += c; accs += s;
    __syncthreads();
  }
  int t = b*LSEQ + l;
  cosm[q*TOK*64 + t*64+hd] = accc*(1.f/32.f);
  sinm[q*TOK*64 + t*64+hd] = accs*(1.f/32.f);
}

// ------------- per-token: B/C rms+rope (f16 in/out), dt(f32)/dA/lam/lamg pack -------------
__global__ __launch_bounds__(256) void ew_kernel(const f16* __restrict__ zxh,
    const float* __restrict__ dtb,
    const float* __restrict__ cosm, const float* __restrict__ sinm,
    const float* __restrict__ dt_bias, const float* __restrict__ A_log,
    const float* __restrict__ B_bias, const float* __restrict__ C_bias,
    const float* __restrict__ Bnw, const float* __restrict__ Cnw,
    f16* __restrict__ Bg, f16* __restrict__ Cg, float4* __restrict__ scal)
{
  int t = blockIdx.x; int tid = threadIdx.x;
  __shared__ float red[256];
  __shared__ float nb[128], nc[128];
  const f16* row = zxh + (size_t)t*DPROJP;
  float v;
  if (tid < 128) v = (float)row[4096 + tid] + B_bias[tid];
  else           v = (float)row[4224 + (tid-128)] + C_bias[tid-128];
  red[tid] = v*v;
  __syncthreads();
  #pragma unroll
  for (int s=64; s>0; s>>=1){
    if ((tid & 127) < s) red[tid] += red[tid + s];
    __syncthreads();
  }
  float ms = red[(tid < 128) ? 0 : 128] * (1.f/128.f);
  float rs = rsqrtf(ms + 1e-5f);
  float w  = (tid < 128) ? Bnw[tid] : Cnw[tid-128];
  float nv = v * rs * w;
  if (tid < 128) nb[tid] = nv; else nc[tid-128] = nv;
  __syncthreads();
  if (tid < 64){
    float c = cosm[t*64+tid] + cosm[TOK*64 + t*64+tid] + cosm[2*TOK*64 + t*64+tid] + cosm[3*TOK*64 + t*64+tid];
    float s = sinm[t*64+tid] + sinm[TOK*64 + t*64+tid] + sinm[2*TOK*64 + t*64+tid] + sinm[3*TOK*64 + t*64+tid];
    float a = nb[tid], bq = nb[tid+64];
    Bg[(size_t)t*128 + tid]      = (f16)(a*c - bq*s);
    Bg[(size_t)t*128 + 64 + tid] = (f16)(bq*c + a*s);
  } else if (tid < 128){
    int i = tid - 64;
    float c = cosm[t*64+i] + cosm[TOK*64 + t*64+i] + cosm[2*TOK*64 + t*64+i] + cosm[3*TOK*64 + t*64+i];
    float s = sinm[t*64+i] + sinm[TOK*64 + t*64+i] + sinm[2*TOK*64 + t*64+i] + sinm[3*TOK*64 + t*64+i];
    float a = nc[i], bq = nc[i+64];
    Cg[(size_t)t*128 + i]      = (f16)(a*c - bq*s);
    Cg[(size_t)t*128 + 64 + i] = (f16)(bq*c + a*s);
  } else if (tid < 160){
    int hh = tid - 128;
    float dtr = dtb[t*32 + hh] + dt_bias[hh];
    float dtv = (dtr > 20.f) ? dtr : log1pf(expf(dtr));
    float dA  = expf(-dtv * expf(A_log[hh]));
    float lr  = (float)row[4384 + hh];
    float lam = 1.f/(1.f + expf(-lr));
    float lg = lam;
    #pragma unroll
    for (int m=1;m<32;m<<=1) lg += __shfl_xor(lg, m, 64);
    lg *= (1.f/32.f);
    scal[(size_t)t*32 + hh] = make_float4(dtv, dA, lam, lg);
  }
}

// ------------- pass 1: per-(b,h,chunk) attention-form local scan, all-f16 LDS -------------
#define CST 136   // f16 row stride for [64][128] tiles
#define SST 72    // f16 row stride for [*][64] tiles
__global__ __launch_bounds__(256, 2) void scanA_kernel(
    const f16* __restrict__ zxh, const f16* __restrict__ Bg,
    const f16* __restrict__ Cg, const float4* __restrict__ scal,
    const float* __restrict__ A_log, const float* __restrict__ Dp,
    f16* __restrict__ ypart, f16* __restrict__ hcarry,
    float* __restrict__ clog, float* __restrict__ AtotB)
{
  __shared__ __align__(16) f16 smC[64*CST];   // C chunk [t][d]; later aliased by S' [t][s]
  __shared__ __align__(16) f16 smB[64*CST];   // B_eff [s][d]
  __shared__ __align__(16) f16 smBT[128*SST]; // B_eff^T * w[s]  [d][s]
  __shared__ __align__(16) f16 smX[64*SST];   // xe^T [p][s]
  __shared__ __align__(16) float sDt[64], sLam[64], sLg[64], sCl[64], sW[64];
  f16* sSp = smC;

  int blk = blockIdx.x;            // (b*32+h)*8 + c
  int c = blk & 7, h = (blk>>3)&31, b = blk>>8;
  int idx = blk;
  int t0 = b*LSEQ + c*CL;
  int tid = threadIdx.x;
  int w = tid >> 6, lane = tid & 63;
  int fr = lane & 15, kq = lane >> 4;

  // ---- phase 0: stage C (f16 direct copy) + wave0 scalar prep ----
  {
    int s = tid >> 2, dq4 = (tid & 3) * 32;
    const ushort* src = (const ushort*)(Cg + (size_t)(t0+s)*128 + dq4);
    ushort* dst = (ushort*)(smC + s*CST + dq4);
    #pragma unroll
    for (int i=0;i<4;i++) *(u16x8*)(dst + i*8) = *(const u16x8*)(src + i*8);
  }
  if (tid < 64){
    float4 sc = scal[(size_t)(t0+tid)*32 + h];
    float a  = __expf(A_log[h]);
    float cl = -sc.x * a * 1.44269504088896f;   // log2(dA)
    #pragma unroll
    for (int m=1; m<64; m<<=1){
      float v = __shfl_up(cl, m, 64);
      if (lane >= m) cl += v;
    }
    float cl63 = __shfl(cl, 63, 64);
    sDt[tid] = sc.x; sLam[tid] = sc.z; sLg[tid] = sc.w;
    sCl[tid] = cl;
    sW[tid]  = exp2f(cl63 - cl) * sc.x;
    clog[(size_t)idx*64 + tid] = cl;
    if (tid == 63) AtotB[idx] = exp2f(cl63);
  }
  __syncthreads();

  // ---- phase 1: stage B_eff (+transposed*w) and xe, f16 ----
  {
    int s = tid >> 2, dq4 = (tid & 3) * 32;
    float lg = sLg[s], wgt = sW[s];
    bool zp = (s == 0 && c == 0);
    const f16* bc_p = Bg + (size_t)(t0+s)*128 + dq4;
    const f16* bp_p = Bg + (size_t)(t0+s-1)*128 + dq4;
    #pragma unroll
    for (int i=0;i<32;i+=4){
      f16x4 bc4 = *(const f16x4*)(bc_p + i);
      f16x4 bp4 = {0,0,0,0};
      if (!zp) bp4 = *(const f16x4*)(bp_p + i);
      f16x4 be4;
      #pragma unroll
      for (int e=0;e<4;e++){
        float bc = (float)bc4[e], bp = (float)bp4[e];
        float be = bp + lg*(bc - bp);
        be4[e] = (f16)be;
        smBT[(dq4+i+e)*SST + s] = (f16)(be * wgt);
      }
      *(f16x4*)(smB + s*CST + dq4 + i) = be4;
    }
  }
  {
    int p = tid & 63, sg = tid >> 6;
    int s0 = sg*16;
    const f16* xbase = zxh + 2048 + h*64 + p;
    float xp_ = 0.f;
    if (!(s0 == 0 && c == 0))
      xp_ = silu_f((float)xbase[(size_t)(t0+s0-1)*DPROJP]);
    #pragma unroll
    for (int i=0;i<16;i++){
      int s = s0 + i;
      float xs = silu_f((float)xbase[(size_t)(t0+s)*DPROJP]);
      smX[p*SST + s] = (f16)(xp_ + sLam[s]*(xs - xp_));
      xp_ = xs;
    }
  }
  __syncthreads();

  // ---- phase 2: GEMM1  S = C @ Beff^T (K=128) ----
  int tq = w >> 1, sq = w & 1;
  f32x4 acc1[2][2] = {};
  #pragma unroll
  for (int kt=0; kt<4; kt++){
    f16x8 ah[2], bh[2];
    #pragma unroll
    for (int i=0;i<2;i++)
      ah[i] = *(const f16x8*)&smC[(tq*32 + i*16 + fr)*CST + kt*32 + kq*8];
    #pragma unroll
    for (int j=0;j<2;j++)
      bh[j] = *(const f16x8*)&smB[(sq*32 + j*16 + fr)*CST + kt*32 + kq*8];
    #pragma unroll
    for (int i=0;i<2;i++)
      #pragma unroll
      for (int j=0;j<2;j++)
        acc1[i][j] = __builtin_amdgcn_mfma_f32_16x16x32_f16(ah[i], bh[j], acc1[i][j], 0,0,0);
  }
  // mask: S'[t,s] = S * exp2(cl_t - cl_s) * dt_s for s<=t else 0
  #pragma unroll
  for (int i=0;i<2;i++){
    int tb = tq*32 + i*16 + kq*4;
    f32x4 clt = *(const f32x4*)&sCl[tb];
    #pragma unroll
    for (int j=0;j<2;j++){
      int scol = sq*32 + j*16 + fr;
      float cls = sCl[scol], dts = sDt[scol];
      #pragma unroll
      for (int q=0;q<4;q++){
        float m = (tb+q >= scol) ? exp2f(clt[q]-cls)*dts : 0.f;
        acc1[i][j][q] *= m;
      }
    }
  }
  __syncthreads();
  #pragma unroll
  for (int i=0;i<2;i++){
    int tb = tq*32 + i*16 + kq*4;
    #pragma unroll
    for (int j=0;j<2;j++){
      int scol = sq*32 + j*16 + fr;
      #pragma unroll
      for (int q=0;q<4;q++)
        sSp[(tb+q)*SST + scol] = (f16)acc1[i][j][q];
    }
  }
  __syncthreads();

  float Dh = Dp[h];
  // ---- phase 3: GEMM2  Y = S' @ Xe  (K=64) + D*xe, write slice0 (f16) ----
  {
    f32x4 acc2[2][2] = {};
    #pragma unroll
    for (int kt=0; kt<2; kt++){
      f16x8 ah[2], bh[2];
      #pragma unroll
      for (int i=0;i<2;i++)
        ah[i] = *(const f16x8*)&sSp[(tq*32 + i*16 + fr)*SST + kt*32 + kq*8];
      #pragma unroll
      for (int j=0;j<2;j++)
        bh[j] = *(const f16x8*)&smX[(sq*32 + j*16 + fr)*SST + kt*32 + kq*8];
      #pragma unroll
      for (int i=0;i<2;i++)
        #pragma unroll
        for (int j=0;j<2;j++)
          acc2[i][j] = __builtin_amdgcn_mfma_f32_16x16x32_f16(ah[i], bh[j], acc2[i][j], 0,0,0);
    }
    #pragma unroll
    for (int i=0;i<2;i++){
      int tb = tq*32 + i*16 + kq*4;
      #pragma unroll
      for (int j=0;j<2;j++){
        int pc = sq*32 + j*16 + fr;
        #pragma unroll
        for (int q=0;q<4;q++){
          float y = acc2[i][j][q] + Dh * (float)smX[pc*SST + tb + q];
          ypart[(size_t)(t0+tb+q)*DSSM + h*64 + pc] = (f16)y;
        }
      }
    }
  }

  // ---- phase 4: GEMM4  H_local = Xe @ (w-scaled B)^T  (K=64), f16 out ----
  {
    f32x4 acc4[2][4] = {};
    int ph = w >> 1, dh = w & 1;
    #pragma unroll
    for (int kt=0; kt<2; kt++){
      f16x8 ah[2], bh[4];
      #pragma unroll
      for (int i=0;i<2;i++)
        ah[i] = *(const f16x8*)&smX[(ph*32 + i*16 + fr)*SST + kt*32 + kq*8];
      #pragma unroll
      for (int j=0;j<4;j++)
        bh[j] = *(const f16x8*)&smBT[(dh*64 + j*16 + fr)*SST + kt*32 + kq*8];
      #pragma unroll
      for (int i=0;i<2;i++)
        #pragma unroll
        for (int j=0;j<4;j++)
          acc4[i][j] = __builtin_amdgcn_mfma_f32_16x16x32_f16(ah[i], bh[j], acc4[i][j], 0,0,0);
    }
    size_t hb = (size_t)idx * 64 * 128;
    #pragma unroll
    for (int i=0;i<2;i++){
      int pb = ph*32 + i*16 + kq*4;
      #pragma unroll
      for (int j=0;j<4;j++){
        int dc = dh*64 + j*16 + fr;
        #pragma unroll
        for (int q=0;q<4;q++)
          hcarry[hb + (size_t)(pb+q)*128 + dc] = (f16)acc4[i][j][q];
      }
    }
  }
}

// ------------- pass 2: propagate carries across chunks (f16 storage, f32 math) -------------
__global__ __launch_bounds__(256) void scan2_kernel(f16* __restrict__ hcarry,
    const float* __restrict__ AtotB)
{
  int idx = blockIdx.x*256 + threadIdx.x;
  int d = idx & 127, pp = (idx >> 7) & 63, h = (idx >> 13) & 31, b = idx >> 18;
  size_t base = ((size_t)(b*32+h)*512 + pp)*128 + d;
  float Hin = 0.f;
  #pragma unroll
  for (int c=0; c<NCH; c++){
    float Atot = AtotB[(b*32+h)*8 + c];
    float S = (float)hcarry[base + (size_t)c*8192];
    hcarry[base + (size_t)c*8192] = (f16)Hin;
    Hin = Atot*Hin + S;
  }
}

// ------------- pass 3: Y2 = exp2(cl_t) * C @ Hin^T  (K=128), f16 LDS, write slice1 f16 -------------
__global__ __launch_bounds__(256) void scanB_kernel(
    const f16* __restrict__ Cg, const f16* __restrict__ hcarry,
    const float* __restrict__ clog, f16* __restrict__ ypart)
{
  __shared__ __align__(16) f16 smC[64*CST];
  __shared__ __align__(16) f16 smH[64*CST];   // Hin [p][d]
  __shared__ __align__(16) float sK[64];
  int blk = blockIdx.x;
  int c = blk & 7, h = (blk>>3)&31, b = blk>>8;
  int idx = blk;
  int t0 = b*LSEQ + c*CL;
  int tid = threadIdx.x;
  int w = tid >> 6, lane = tid & 63;
  int fr = lane & 15, kq = lane >> 4;
  {
    int s = tid >> 2, dq4 = (tid & 3) * 32;
    const ushort* src = (const ushort*)(Cg + (size_t)(t0+s)*128 + dq4);
    ushort* dst = (ushort*)(smC + s*CST + dq4);
    #pragma unroll
    for (int i=0;i<4;i++) *(u16x8*)(dst + i*8) = *(const u16x8*)(src + i*8);
    const ushort* hs = (const ushort*)(hcarry + (size_t)idx*8192 + (size_t)s*128 + dq4);
    ushort* hd = (ushort*)(smH + s*CST + dq4);
    #pragma unroll
    for (int i=0;i<4;i++) *(u16x8*)(hd + i*8) = *(const u16x8*)(hs + i*8);
  }
  if (tid < 64) sK[tid] = exp2f(clog[(size_t)idx*64 + tid]);
  __syncthreads();

  int tq = w >> 1, pq = w & 1;
  f32x4 acc[2][2] = {};
  #pragma unroll
  for (int kt=0; kt<4; kt++){
    f16x8 ah[2], bh[2];
    #pragma unroll
    for (int i=0;i<2;i++)
      ah[i] = *(const f16x8*)&smC[(tq*32 + i*16 + fr)*CST + kt*32 + kq*8];
    #pragma unroll
    for (int j=0;j<2;j++)
      bh[j] = *(const f16x8*)&smH[(pq*32 + j*16 + fr)*CST + kt*32 + kq*8];
    #pragma unroll
    for (int i=0;i<2;i++)
      #pragma unroll
      for (int j=0;j<2;j++)
        acc[i][j] = __builtin_amdgcn_mfma_f32_16x16x32_f16(ah[i], bh[j], acc[i][j], 0,0,0);
  }
  #pragma unroll
  for (int i=0;i<2;i++){
    int tb = tq*32 + i*16 + kq*4;
    f32x4 kv = *(const f32x4*)&sK[tb];
    #pragma unroll
    for (int j=0;j<2;j++){
      int pc = pq*32 + j*16 + fr;
      #pragma unroll
      for (int q=0;q<4;q++)
        ypart[(size_t)TOK*DSSM + (size_t)(t0+tb+q)*DSSM + h*64 + pc] = (f16)(acc[i][j][q]*kv[q]);
    }
  }
}

// ------------- final: sum 2 f16 partials, *silu(z f16), rms*norm_w -> f16 -------------
__global__ __launch_bounds__(256) void fin_kernel(const f16* __restrict__ zxh,
    const f16* __restrict__ ypart, const float* __restrict__ normw,
    f16* __restrict__ yf)
{
  int t = blockIdx.x; int tid = threadIdx.x;
  __shared__ float red[256];
  float vloc[8];
  float ss = 0.f;
  #pragma unroll
  for (int i=0;i<8;i++){
    int cc = tid + i*256;
    float y = (float)ypart[(size_t)t*DSSM + cc]
            + (float)ypart[(size_t)(TOK + t)*DSSM + cc];
    float z = (float)zxh[(size_t)t*DPROJP + cc];
    float v = y * (z / (1.f + expf(-z)));
    vloc[i] = v; ss += v*v;
  }
  red[tid] = ss; __syncthreads();
  #pragma unroll
  for (int s=128; s>0; s>>=1){ if (tid < s) red[tid] += red[tid+s]; __syncthreads(); }
  float rs = rsqrtf(red[0]*(1.f/2048.f) + 1e-5f);
  #pragma unroll
  for (int i=0;i<8;i++){
    int cc = tid + i*256;
    yf[(size_t)t*DSSM + cc] = (f16)(vloc[i]*rs*normw[cc]);
  }
}

extern "C" void kernel_launch(void* const* d_in, const int* in_sizes, int n_in,
                              void* d_out, int out_size, void* d_ws, size_t ws_size,
                              hipStream_t stream)
{
  const float* u      = (const float*)d_in[0];
  const float* W_in   = (const float*)d_in[1];
  const float* W_out  = (const float*)d_in[2];
  const float* dt_bias= (const float*)d_in[3];
  const float* A_log  = (const float*)d_in[4];
  const float* Dp     = (const float*)d_in[5];
  const float* B_bias = (const float*)d_in[6];
  const float* C_bias = (const float*)d_in[7];
  const float* Bnw    = (const float*)d_in[8];
  const float* Cnw    = (const float*)d_in[9];
  const float* normw  = (const float*)d_in[10];
  float* out = (float*)d_out;

  char* ws = (char*)d_ws;
  size_t o = 0;
  auto alloc = [&](size_t bytes)->char*{
    char* r = ws + o; o = (o + bytes + 255) & ~(size_t)255; return r;
  };
  f16*  WT   = (f16*)alloc((size_t)DPROJP*DMODEL*2);
  f16*  WoT  = (f16*)alloc((size_t)DMODEL*DSSM*2);
  f16*  uhf  = (f16*)alloc((size_t)TOK*DMODEL*2);
  f16*  yf   = (f16*)alloc((size_t)TOK*DSSM*2);
  f16*  zxh  = (f16*)alloc((size_t)TOK*DPROJP*2);
  float* dtb = (float*)alloc((size_t)TOK*32*4);
  f16*   thT  = (f16*)alloc((size_t)2*2048*512*2);
  float*  cosm = (float*)alloc((size_t)4*TOK*64*4);
  float*  sinm = (float*)alloc((size_t)4*TOK*64*4);
  f16*   Bgb  = (f16*)alloc((size_t)TOK*128*2);
  f16*   Cgb  = (f16*)alloc((size_t)TOK*128*2);
  float4* scal = (float4*)alloc((size_t)TOK*32*16);
  f16*   ypart= (f16*)alloc((size_t)2*TOK*DSSM*2);
  f16*   hcarry=(f16*)alloc((size_t)2*32*NCH*64*128*2);
  float*  clog = (float*)alloc((size_t)512*64*4);
  float*  AtotB= (float*)alloc((size_t)512*4);
  f16*   Cpart =(f16*)alloc((size_t)4*TOK*DMODEL*2);

  // fused prep: W_in^T, W_out^T, u -> f16
  prep_kernel<<<dim3(9600), dim3(256), 0, stream>>>(W_in, W_out, u, WT, WoT, uhf);

  // in-proj: zxh f16 + dtb f32 (coalesced epilogue only)
  gemmh_kernel<0><<<dim3(408), dim3(512), 0, stream>>>(uhf, WT, zxh, dtb, DMODEL, DMODEL, DPROJP, 51, 51);

  // theta transpose (f16 -> f16) + cumsum + cos/sin
  thT_kernel<<<dim3(32, 8, 2), dim3(256), 0, stream>>>(zxh, thT);
  cum2_kernel<<<dim3(512), dim3(512), 0, stream>>>(thT, cosm, sinm);

  // per-token elementwise
  ew_kernel<<<dim3(TOK), dim3(256), 0, stream>>>(zxh, dtb, cosm, sinm, dt_bias, A_log,
                                                 B_bias, C_bias, Bnw, Cnw, Bgb, Cgb, scal);

  // attention-form chunked scan (f16 intermediates)
  scanA_kernel<<<dim3(512),  dim3(256), 0, stream>>>(zxh, Bgb, Cgb, scal, A_log, Dp,
                                                     ypart, hcarry, clog, AtotB);
  scan2_kernel<<<dim3(2048), dim3(256), 0, stream>>>(hcarry, AtotB);
  scanB_kernel<<<dim3(512),  dim3(256), 0, stream>>>(Cgb, hcarry, clog, ypart);

  // gate + rms -> f16
  fin_kernel<<<dim3(TOK), dim3(256), 0, stream>>>(zxh, ypart, normw, yf);

  // out-proj: split-K=4, f16 partials
  gemmh_kernel<1><<<dim3(256), dim3(512), 0, stream>>>(yf, WoT, Cpart, nullptr, DSSM, 512, DMODEL, 8, 32);
  red4_kernel<<<dim3(TOK*DMODEL/1024), dim3(256), 0, stream>>>(Cpart, out);
}